// Round 1
// baseline (209.596 us; speedup 1.0000x reference)
//
#include <hip/hip_runtime.h>

typedef _Float16 f16;
typedef __attribute__((ext_vector_type(4))) _Float16 f16x4;
typedef __attribute__((ext_vector_type(8))) _Float16 f16x8;
typedef __attribute__((ext_vector_type(4))) float f32x4;

#define MFMA16(a, b, c) __builtin_amdgcn_mfma_f32_16x16x32_f16((a), (b), (c), 0, 0, 0)

__device__ __forceinline__ void gload_lds16(const void* g, void* l) {
  __builtin_amdgcn_global_load_lds(
      (const __attribute__((address_space(1))) void*)g,
      (__attribute__((address_space(3))) void*)l, 16, 0, 0);
}

// ---------------- convert fp32 -> f16 (vectorized) ----------------
__global__ __launch_bounds__(256) void k_convert(const float* __restrict__ in,
                                                 f16* __restrict__ out, int n4) {
  int i = blockIdx.x * blockDim.x + threadIdx.x;
  int stride = gridDim.x * blockDim.x;
  for (; i < n4; i += stride) {
    float4 v = ((const float4*)in)[i];
    f16x4 o;
    o.x = (f16)v.x; o.y = (f16)v.y; o.z = (f16)v.z; o.w = (f16)v.w;
    ((f16x4*)out)[i] = o;
  }
}

// ------------- transpose [K][N] fp32 -> [N][K] f16 (LDS tiled) -------------
__global__ __launch_bounds__(256) void k_transposeW(const float* __restrict__ in,
                                                    f16* __restrict__ out,
                                                    int K, int N) {
  __shared__ float tile[64][65];
  int n0 = blockIdx.x * 64, k0 = blockIdx.y * 64;
  int c = threadIdx.x & 63, r4 = threadIdx.x >> 6;
#pragma unroll
  for (int i = 0; i < 16; ++i) {
    int r = i * 4 + r4;
    tile[r][c] = in[(size_t)(k0 + r) * N + n0 + c];
  }
  __syncthreads();
#pragma unroll
  for (int i = 0; i < 16; ++i) {
    int r = i * 4 + r4;
    out[(size_t)(n0 + r) * K + k0 + c] = (f16)tile[c][r];
  }
}

// ------------- transpose V [t][d] -> Vt [d][t] per (b,h), f16 -------------
__global__ __launch_bounds__(256) void k_transposeV(const f16* __restrict__ in,
                                                    f16* __restrict__ out) {
  __shared__ f16 tile[64][65];
  int bh = blockIdx.x;
  int t0 = blockIdx.y * 64;
  int c = threadIdx.x & 63, r4 = threadIdx.x >> 6;
  const f16* ip = in + (size_t)bh * 2048 * 64;
  f16* op = out + (size_t)bh * 64 * 2048;
#pragma unroll
  for (int i = 0; i < 16; ++i) {
    int r = i * 4 + r4;
    tile[r][c] = ip[(size_t)(t0 + r) * 64 + c];
  }
  __syncthreads();
#pragma unroll
  for (int i = 0; i < 16; ++i) {
    int r = i * 4 + r4;  // d index
    op[(size_t)r * 2048 + t0 + c] = tile[c][r];
  }
}

// ---------------- 128x128 f16 MFMA GEMM, A[M][K] * BT[N][K]^T ----------------
// mode 0: scatter columns to Q/K/V [b*12+h][t][d] (f16)
// mode 1: out[row][col] = acc + bias[col] (fp32)
__global__ __launch_bounds__(256) void k_gemm(
    const f16* __restrict__ A, const f16* __restrict__ BT,
    int M, int N, int K, int mode,
    f16* __restrict__ Qo, f16* __restrict__ Ko, f16* __restrict__ Vo,
    const float* __restrict__ bias, float* __restrict__ out) {
  __shared__ f16 As[128 * 32];
  __shared__ f16 Bs[128 * 32];
  int tid = threadIdx.x;
  int wv = tid >> 6;
  int lane = tid & 63;
  int lr = lane & 15, lc = lane >> 4;
  int m0 = blockIdx.x * 128, n0 = blockIdx.y * 128;
  int wm = (wv >> 1) * 64, wn = (wv & 1) * 64;
  f32x4 acc[4][4] = {};
  int nK = K >> 5;
  for (int kt = 0; kt < nK; ++kt) {
    int k0 = kt << 5;
#pragma unroll
    for (int i = 0; i < 2; ++i) {
      int g = i * 256 + tid;
      gload_lds16(A + (size_t)(m0 + (g >> 2)) * K + k0 + (g & 3) * 8,
                  As + (size_t)(i * 256 + (tid & 192)) * 8);
    }
#pragma unroll
    for (int i = 0; i < 2; ++i) {
      int g = i * 256 + tid;
      gload_lds16(BT + (size_t)(n0 + (g >> 2)) * K + k0 + (g & 3) * 8,
                  Bs + (size_t)(i * 256 + (tid & 192)) * 8);
    }
    __syncthreads();
    f16x8 af[4], bf[4];
#pragma unroll
    for (int mi = 0; mi < 4; ++mi)
      af[mi] = *(const f16x8*)&As[(wm + mi * 16 + lr) * 32 + lc * 8];
#pragma unroll
    for (int ni = 0; ni < 4; ++ni)
      bf[ni] = *(const f16x8*)&Bs[(wn + ni * 16 + lr) * 32 + lc * 8];
#pragma unroll
    for (int mi = 0; mi < 4; ++mi)
#pragma unroll
      for (int ni = 0; ni < 4; ++ni)
        acc[mi][ni] = MFMA16(af[mi], bf[ni], acc[mi][ni]);
    __syncthreads();
  }
  if (mode == 0) {
#pragma unroll
    for (int ni = 0; ni < 4; ++ni) {
      int col = n0 + wn + ni * 16 + lr;
      int s = col / 768;
      int hh = (col - s * 768) >> 6;
      int d = col & 63;
      f16* dst = (s == 0) ? Qo : (s == 1) ? Ko : Vo;
#pragma unroll
      for (int mi = 0; mi < 4; ++mi)
#pragma unroll
        for (int r = 0; r < 4; ++r) {
          int row = m0 + wm + mi * 16 + lc * 4 + r;
          int b = row >> 11, t = row & 2047;
          dst[((size_t)(b * 12 + hh) * 2048 + t) * 64 + d] =
              (f16)acc[mi][ni][r];
        }
    }
  } else {
#pragma unroll
    for (int ni = 0; ni < 4; ++ni) {
      int col = n0 + wn + ni * 16 + lr;
      float bv = bias[col];
#pragma unroll
      for (int mi = 0; mi < 4; ++mi)
#pragma unroll
        for (int r = 0; r < 4; ++r) {
          int row = m0 + wm + mi * 16 + lc * 4 + r;
          out[(size_t)row * 768 + col] = acc[mi][ni][r] + bv;
        }
    }
  }
}

// ---------------- causal softplus-normalized attention ----------------
// grid (24 bh, 16 q-tiles), 4 waves; wave owns 32 q-rows. No barriers.
__global__ __launch_bounds__(256) void k_attn(const f16* __restrict__ Q,
                                              const f16* __restrict__ K,
                                              const f16* __restrict__ Vt,
                                              f16* __restrict__ Ab) {
  __shared__ f16 wlds[4][2048];  // per-wave [32 rows][64 keys], XOR-swizzled
  int tid = threadIdx.x, wv = tid >> 6, lane = tid & 63;
  int lr = lane & 15, lc = lane >> 4;
  int bh = blockIdx.x, qi = blockIdx.y;
  int q0 = qi * 128;
  int b = bh / 12, h = bh - b * 12;
  const f16* Qp = Q + (size_t)bh * 2048 * 64;
  const f16* Kp = K + (size_t)bh * 2048 * 64;
  const f16* Vp = Vt + (size_t)bh * 64 * 2048;
  int qw = q0 + wv * 32;
  f16x8 qf[2][2];
#pragma unroll
  for (int mi = 0; mi < 2; ++mi)
#pragma unroll
    for (int kh = 0; kh < 2; ++kh)
      qf[mi][kh] =
          *(const f16x8*)&Qp[(size_t)(qw + mi * 16 + lr) * 64 + kh * 32 + lc * 8];
  f32x4 o[2][4] = {};
  float rs[2][4] = {};
  f16* wb = wlds[wv];
  int nkt = (qw >> 6) + 1;
  for (int kt = 0; kt < nkt; ++kt) {
    int kb = kt << 6;
    f32x4 s[2][4] = {};
#pragma unroll
    for (int ni = 0; ni < 4; ++ni) {
#pragma unroll
      for (int kh = 0; kh < 2; ++kh) {
        f16x8 kf =
            *(const f16x8*)&Kp[(size_t)(kb + ni * 16 + lr) * 64 + kh * 32 + lc * 8];
        s[0][ni] = MFMA16(qf[0][kh], kf, s[0][ni]);
        s[1][ni] = MFMA16(qf[1][kh], kf, s[1][ni]);
      }
    }
    // softplus + causal mask + rowsum + swizzled LDS write
#pragma unroll
    for (int mi = 0; mi < 2; ++mi) {
      float part[4] = {0.f, 0.f, 0.f, 0.f};
#pragma unroll
      for (int ni = 0; ni < 4; ++ni) {
        int key = kb + ni * 16 + lr;
        int cb = ni * 16 + lr;
#pragma unroll
        for (int r = 0; r < 4; ++r) {
          int rloc = mi * 16 + lc * 4 + r;
          int qrow = qw + rloc;
          float x = s[mi][ni][r] * 0.125f;
          float e = __expf(-fabsf(x));
          float w = fmaxf(x, 0.f) + __logf(1.f + e);
          w = (key <= qrow) ? w : 0.f;
          part[r] += w;
          wb[rloc * 64 + (((cb >> 3) ^ (rloc & 7)) << 3) + (cb & 7)] = (f16)w;
        }
      }
#pragma unroll
      for (int r = 0; r < 4; ++r) {
        float p = part[r];
        p += __shfl_xor(p, 1);
        p += __shfl_xor(p, 2);
        p += __shfl_xor(p, 4);
        p += __shfl_xor(p, 8);
        rs[mi][r] += p;
      }
    }
    // PV: A = weights from LDS, B = Vt rows straight from global
#pragma unroll
    for (int kh = 0; kh < 2; ++kh) {
      f16x8 pa[2];
#pragma unroll
      for (int mi = 0; mi < 2; ++mi) {
        int rloc = mi * 16 + lr;
        pa[mi] =
            *(const f16x8*)&wb[rloc * 64 + ((((kh << 2) + lc) ^ (rloc & 7)) << 3)];
      }
#pragma unroll
      for (int di = 0; di < 4; ++di) {
        f16x8 vf =
            *(const f16x8*)&Vp[(size_t)(di * 16 + lr) * 2048 + kb + kh * 32 + lc * 8];
        o[0][di] = MFMA16(pa[0], vf, o[0][di]);
        o[1][di] = MFMA16(pa[1], vf, o[1][di]);
      }
    }
  }
  // normalize + store f16 attn output in [b*T+t][h*64+d]
#pragma unroll
  for (int mi = 0; mi < 2; ++mi)
#pragma unroll
    for (int r = 0; r < 4; ++r) {
      int rloc = mi * 16 + lc * 4 + r;
      float inv = 1.0f / rs[mi][r];
#pragma unroll
      for (int di = 0; di < 4; ++di)
        Ab[((size_t)b * 2048 + qw + rloc) * 768 + h * 64 + di * 16 + lr] =
            (f16)(o[mi][di][r] * inv);
    }
}

// ---------------- host ----------------
extern "C" void kernel_launch(void* const* d_in, const int* in_sizes, int n_in,
                              void* d_out, int out_size, void* d_ws,
                              size_t ws_size, hipStream_t stream) {
  const float* x = (const float*)d_in[0];
  const float* Wqkv = (const float*)d_in[1];
  const float* Wproj = (const float*)d_in[2];
  const float* bproj = (const float*)d_in[3];
  float* out = (float*)d_out;
  char* ws = (char*)d_ws;

  f16* xb     = (f16*)(ws + 0);         //  4096x768          6,291,456 B
  f16* WqkvT  = (f16*)(ws + 6291456);   //  2304x768          3,538,944 B
  f16* WprojT = (f16*)(ws + 9830400);   //   768x768          1,179,648 B
  f16* Qb     = (f16*)(ws + 11010048);  //  24x2048x64        6,291,456 B
  f16* Kb     = (f16*)(ws + 17301504);  //  24x2048x64        6,291,456 B
  f16* Vb     = (f16*)(ws + 23592960);  //  24x2048x64        6,291,456 B
  f16* Vtb    = (f16*)(ws + 29884416);  //  24x64x2048        6,291,456 B
  f16* Ab     = (f16*)(ws + 36175872);  //  4096x768          6,291,456 B
  // total 42,467,328 B

  k_convert<<<1024, 256, 0, stream>>>(x, xb, (4096 * 768) / 4);
  k_transposeW<<<dim3(36, 12), 256, 0, stream>>>(Wqkv, WqkvT, 768, 2304);
  k_transposeW<<<dim3(12, 12), 256, 0, stream>>>(Wproj, WprojT, 768, 768);
  k_gemm<<<dim3(32, 18), 256, 0, stream>>>(xb, WqkvT, 4096, 2304, 768, 0, Qb,
                                           Kb, Vb, nullptr, nullptr);
  k_transposeV<<<dim3(24, 32), 256, 0, stream>>>(Vb, Vtb);
  k_attn<<<dim3(24, 16), 256, 0, stream>>>(Qb, Kb, Vtb, Ab);
  k_gemm<<<dim3(32, 6), 256, 0, stream>>>(Ab, WprojT, 4096, 768, 768, 1,
                                          nullptr, nullptr, nullptr, bproj, out);
}

// Round 2
// 143.238 us; speedup vs baseline: 1.4633x; 1.4633x over previous
//
#include <hip/hip_runtime.h>

typedef _Float16 f16;
typedef __attribute__((ext_vector_type(4))) _Float16 f16x4;
typedef __attribute__((ext_vector_type(8))) _Float16 f16x8;
typedef __attribute__((ext_vector_type(4))) float f32x4;

#define MFMA16(a, b, c) __builtin_amdgcn_mfma_f32_16x16x32_f16((a), (b), (c), 0, 0, 0)

__device__ __forceinline__ void gload_lds16(const void* g, void* l) {
  __builtin_amdgcn_global_load_lds(
      (const __attribute__((address_space(1))) void*)g,
      (__attribute__((address_space(3))) void*)l, 16, 0, 0);
}

// ---------------- convert fp32 -> f16 (vectorized) ----------------
__global__ __launch_bounds__(256) void k_convert(const float* __restrict__ in,
                                                 f16* __restrict__ out, int n4) {
  int i = blockIdx.x * blockDim.x + threadIdx.x;
  int stride = gridDim.x * blockDim.x;
  for (; i < n4; i += stride) {
    float4 v = ((const float4*)in)[i];
    f16x4 o;
    o.x = (f16)v.x; o.y = (f16)v.y; o.z = (f16)v.z; o.w = (f16)v.w;
    ((f16x4*)out)[i] = o;
  }
}

// ------------- transpose [K][N] fp32 -> [N][K] f16 (LDS tiled) -------------
__global__ __launch_bounds__(256) void k_transposeW(const float* __restrict__ in,
                                                    f16* __restrict__ out,
                                                    int K, int N) {
  __shared__ float tile[64][65];
  int n0 = blockIdx.x * 64, k0 = blockIdx.y * 64;
  int c = threadIdx.x & 63, r4 = threadIdx.x >> 6;
#pragma unroll
  for (int i = 0; i < 16; ++i) {
    int r = i * 4 + r4;
    tile[r][c] = in[(size_t)(k0 + r) * N + n0 + c];
  }
  __syncthreads();
#pragma unroll
  for (int i = 0; i < 16; ++i) {
    int r = i * 4 + r4;
    out[(size_t)(n0 + r) * K + k0 + c] = (f16)tile[c][r];
  }
}

// ---------------- 128x128 f16 MFMA GEMM, A[M][K] * BT[N][K]^T ----------------
// mode 0: scatter columns to Q/K [bh][t][d] (f16) and V transposed [bh][d][t]
// mode 1: out[row][col] = acc + bias[col] (fp32)
__global__ __launch_bounds__(256) void k_gemm(
    const f16* __restrict__ A, const f16* __restrict__ BT,
    int M, int N, int K, int mode,
    f16* __restrict__ Qo, f16* __restrict__ Ko, f16* __restrict__ Vt,
    const float* __restrict__ bias, float* __restrict__ out) {
  __shared__ f16 As[128 * 32];
  __shared__ f16 Bs[128 * 32];
  int tid = threadIdx.x;
  int wv = tid >> 6;
  int lane = tid & 63;
  int lr = lane & 15, lc = lane >> 4;
  int m0 = blockIdx.x * 128, n0 = blockIdx.y * 128;
  int wm = (wv >> 1) * 64, wn = (wv & 1) * 64;
  f32x4 acc[4][4] = {};
  int nK = K >> 5;
  for (int kt = 0; kt < nK; ++kt) {
    int k0 = kt << 5;
#pragma unroll
    for (int i = 0; i < 2; ++i) {
      int g = i * 256 + tid;
      gload_lds16(A + (size_t)(m0 + (g >> 2)) * K + k0 + (g & 3) * 8,
                  As + (size_t)(i * 256 + (tid & 192)) * 8);
    }
#pragma unroll
    for (int i = 0; i < 2; ++i) {
      int g = i * 256 + tid;
      gload_lds16(BT + (size_t)(n0 + (g >> 2)) * K + k0 + (g & 3) * 8,
                  Bs + (size_t)(i * 256 + (tid & 192)) * 8);
    }
    __syncthreads();
    f16x8 af[4], bf[4];
#pragma unroll
    for (int mi = 0; mi < 4; ++mi)
      af[mi] = *(const f16x8*)&As[(wm + mi * 16 + lr) * 32 + lc * 8];
#pragma unroll
    for (int ni = 0; ni < 4; ++ni)
      bf[ni] = *(const f16x8*)&Bs[(wn + ni * 16 + lr) * 32 + lc * 8];
#pragma unroll
    for (int mi = 0; mi < 4; ++mi)
#pragma unroll
      for (int ni = 0; ni < 4; ++ni)
        acc[mi][ni] = MFMA16(af[mi], bf[ni], acc[mi][ni]);
    __syncthreads();
  }
  if (mode == 0) {
#pragma unroll
    for (int ni = 0; ni < 4; ++ni) {
      int col = n0 + wn + ni * 16 + lr;
      int s = col / 768;
      int hh = (col - s * 768) >> 6;
      int d = col & 63;
      if (s == 2) {
        // V: write transposed [bh][d][t], 4 consecutive t per (mi)
#pragma unroll
        for (int mi = 0; mi < 4; ++mi) {
          int row0 = m0 + wm + mi * 16 + lc * 4;
          int b = row0 >> 11, t = row0 & 2047;
          f16x4 tv;
#pragma unroll
          for (int r = 0; r < 4; ++r) tv[r] = (f16)acc[mi][ni][r];
          *(f16x4*)&Vt[((size_t)(b * 12 + hh) * 64 + d) * 2048 + t] = tv;
        }
      } else {
        f16* dst = (s == 0) ? Qo : Ko;
#pragma unroll
        for (int mi = 0; mi < 4; ++mi)
#pragma unroll
          for (int r = 0; r < 4; ++r) {
            int row = m0 + wm + mi * 16 + lc * 4 + r;
            int b = row >> 11, t = row & 2047;
            dst[((size_t)(b * 12 + hh) * 2048 + t) * 64 + d] =
                (f16)acc[mi][ni][r];
          }
      }
    }
  } else {
#pragma unroll
    for (int ni = 0; ni < 4; ++ni) {
      int col = n0 + wn + ni * 16 + lr;
      float bv = bias[col];
#pragma unroll
      for (int mi = 0; mi < 4; ++mi)
#pragma unroll
        for (int r = 0; r < 4; ++r) {
          int row = m0 + wm + mi * 16 + lc * 4 + r;
          out[(size_t)row * 768 + col] = acc[mi][ni][r] + bv;
        }
    }
  }
}

// ---------------- causal softplus-normalized attention, split-K ----------------
// 1-wave blocks (64 thr), 32 q-rows per wave. grid (24 bh, 96):
//  y in [0,32):  qt = 32+y, keys [0,1024)   -> partial chunk0 (no mask)
//  y in [32,64): qt = 95-y, keys [1024,row] -> partial chunk1 (diag mask)
//  y in [64,96): qt = 95-y (rows < 1024), keys [0,row] -> final output
__global__ __launch_bounds__(64) void k_attn(
    const f16* __restrict__ Q, const f16* __restrict__ K,
    const f16* __restrict__ Vt, f16* __restrict__ Ab,
    float* __restrict__ Op0, float* __restrict__ Op1,
    float* __restrict__ rs0, float* __restrict__ rs1) {
  __shared__ f16 wb[2048];  // [32 rows][64 cols] XOR-swizzled P tile
  int lane = threadIdx.x;
  int lr = lane & 15, lc = lane >> 4;
  int bh = blockIdx.x;
  int y = blockIdx.y;
  int qt, kt0, nfull, mode;
  bool diag;
  if (y < 32)      { qt = 32 + y; kt0 = 0;  nfull = 16;                    diag = false; mode = 1; }
  else if (y < 64) { qt = 95 - y; kt0 = 16; nfull = (qt * 32 - 1024) >> 6; diag = true;  mode = 2; }
  else             { qt = 95 - y; kt0 = 0;  nfull = (qt * 32) >> 6;        diag = true;  mode = 0; }
  int qw = qt * 32;
  int b = bh / 12, h = bh - b * 12;
  const f16* Qp = Q + (size_t)bh * 2048 * 64;
  const f16* Kp = K + (size_t)bh * 2048 * 64;
  const f16* Vp = Vt + (size_t)bh * 64 * 2048;

  const f16 a16 = (f16)0.18033688f;  // 0.125 * log2(e): fold scale into Q
  f16x8 qf[2][2];
#pragma unroll
  for (int mi = 0; mi < 2; ++mi)
#pragma unroll
    for (int kh = 0; kh < 2; ++kh) {
      qf[mi][kh] =
          *(const f16x8*)&Qp[(size_t)(qw + mi * 16 + lr) * 64 + kh * 32 + lc * 8];
      qf[mi][kh] *= a16;
    }

  f32x4 o[2][4] = {};
  float rsl[2][4] = {};  // per-lane partial row sums

  auto do_tile = [&](int kb, bool maskit) {
    f32x4 s[2][4] = {};
#pragma unroll
    for (int ni = 0; ni < 4; ++ni)
#pragma unroll
      for (int kh = 0; kh < 2; ++kh) {
        f16x8 kf =
            *(const f16x8*)&Kp[(size_t)(kb + ni * 16 + lr) * 64 + kh * 32 + lc * 8];
        s[0][ni] = MFMA16(qf[0][kh], kf, s[0][ni]);
        s[1][ni] = MFMA16(qf[1][kh], kf, s[1][ni]);
      }
    // softplus(x) with z = x*log2e already: w = ln2*(max(z,0)+log2(1+2^-|z|))
#pragma unroll
    for (int mi = 0; mi < 2; ++mi)
#pragma unroll
      for (int ni = 0; ni < 4; ++ni) {
        int cb = ni * 16 + lr;
#pragma unroll
        for (int r = 0; r < 4; ++r) {
          int rloc = mi * 16 + lc * 4 + r;
          float z = s[mi][ni][r];
          float t = __builtin_amdgcn_exp2f(-fabsf(z));
          float w = (fmaxf(z, 0.f) + __builtin_amdgcn_logf(1.f + t)) *
                    0.6931471805599453f;
          if (maskit) w = (kb + cb <= qw + rloc) ? w : 0.f;
          rsl[mi][r] += w;
          wb[rloc * 64 + (((cb >> 3) ^ (rloc & 7)) << 3) + (cb & 7)] = (f16)w;
        }
      }
    // PV: A = P from LDS, B = Vt rows from global
#pragma unroll
    for (int kh = 0; kh < 2; ++kh) {
      f16x8 pa[2];
#pragma unroll
      for (int mi = 0; mi < 2; ++mi) {
        int rloc = mi * 16 + lr;
        pa[mi] =
            *(const f16x8*)&wb[rloc * 64 + ((((kh << 2) + lc) ^ (rloc & 7)) << 3)];
      }
#pragma unroll
      for (int di = 0; di < 4; ++di) {
        f16x8 vf =
            *(const f16x8*)&Vp[(size_t)(di * 16 + lr) * 2048 + kb + kh * 32 + lc * 8];
        o[0][di] = MFMA16(pa[0], vf, o[0][di]);
        o[1][di] = MFMA16(pa[1], vf, o[1][di]);
      }
    }
  };

  for (int kt = kt0; kt < kt0 + nfull; ++kt) do_tile(kt << 6, false);
  if (diag) do_tile(qw & ~63, true);

  // row-sum reduce across the 16 lr lanes (rows indexed by lc)
#pragma unroll
  for (int mi = 0; mi < 2; ++mi)
#pragma unroll
    for (int r = 0; r < 4; ++r) {
      float p = rsl[mi][r];
      p += __shfl_xor(p, 1);
      p += __shfl_xor(p, 2);
      p += __shfl_xor(p, 4);
      p += __shfl_xor(p, 8);
      rsl[mi][r] = p;
    }

  if (mode == 0) {
#pragma unroll
    for (int mi = 0; mi < 2; ++mi)
#pragma unroll
      for (int r = 0; r < 4; ++r) {
        int rloc = mi * 16 + lc * 4 + r;
        float inv = 1.0f / rsl[mi][r];
#pragma unroll
        for (int di = 0; di < 4; ++di)
          Ab[((size_t)b * 2048 + qw + rloc) * 768 + h * 64 + di * 16 + lr] =
              (f16)(o[mi][di][r] * inv);
      }
  } else {
    float* OP = (mode == 1) ? Op0 : Op1;
    float* RS = (mode == 1) ? rs0 : rs1;
    int pr0 = qw - 1024;
#pragma unroll
    for (int mi = 0; mi < 2; ++mi)
#pragma unroll
      for (int r = 0; r < 4; ++r) {
        int rloc = mi * 16 + lc * 4 + r;
        if (lr == 0) RS[bh * 1024 + pr0 + rloc] = rsl[mi][r];
#pragma unroll
        for (int di = 0; di < 4; ++di)
          OP[((size_t)bh * 1024 + pr0 + rloc) * 64 + di * 16 + lr] =
              o[mi][di][r];
      }
  }
}

// ---------------- combine split-K partials (rows 1024..2047) ----------------
__global__ __launch_bounds__(256) void k_combine(
    const float* __restrict__ Op0, const float* __restrict__ Op1,
    const float* __restrict__ rs0, const float* __restrict__ rs1,
    f16* __restrict__ Ab) {
  int i = blockIdx.x * 256 + threadIdx.x;  // one f32x4 per thread
  int e = i << 2;
  int bh = e >> 16;           // 1024*64 elems per bh
  int rem = e & 65535;
  int pr = rem >> 6, d = rem & 63;
  float inv = 1.0f / (rs0[(bh << 10) + pr] + rs1[(bh << 10) + pr]);
  float4 a = ((const float4*)Op0)[i];
  float4 c = ((const float4*)Op1)[i];
  f16x4 o4;
  o4[0] = (f16)((a.x + c.x) * inv);
  o4[1] = (f16)((a.y + c.y) * inv);
  o4[2] = (f16)((a.z + c.z) * inv);
  o4[3] = (f16)((a.w + c.w) * inv);
  int b = bh / 12, h = bh - b * 12;
  *(f16x4*)&Ab[((size_t)b * 2048 + 1024 + pr) * 768 + h * 64 + d] = o4;
}

// ---------------- host ----------------
extern "C" void kernel_launch(void* const* d_in, const int* in_sizes, int n_in,
                              void* d_out, int out_size, void* d_ws,
                              size_t ws_size, hipStream_t stream) {
  const float* x = (const float*)d_in[0];
  const float* Wqkv = (const float*)d_in[1];
  const float* Wproj = (const float*)d_in[2];
  const float* bproj = (const float*)d_in[3];
  float* out = (float*)d_out;
  char* ws = (char*)d_ws;

  f16* xb     = (f16*)(ws + 0);         // 4096x768 f16 = 6,291,456 B (dead after gemm1)
  float* Op0  = (float*)(ws + 0);       // alias: 24x1024x64 f32 = 6,291,456 B
  f16* WqkvT  = (f16*)(ws + 6291456);   // 2304x768
  f16* WprojT = (f16*)(ws + 9830400);   // 768x768
  f16* Qb     = (f16*)(ws + 11010048);  // 24x2048x64
  f16* Kb     = (f16*)(ws + 17301504);  // 24x2048x64
  f16* Vtb    = (f16*)(ws + 23592960);  // 24x64x2048 (written by gemm1)
  f16* Ab     = (f16*)(ws + 29884416);  // 4096x768
  float* Op1  = (float*)(ws + 36175872);// 24x1024x64 f32
  float* rs0  = (float*)(ws + 42467328);// 24x1024 f32
  float* rs1  = (float*)(ws + 42565632);// 24x1024 f32
  // total 42,663,936 B

  k_convert<<<1024, 256, 0, stream>>>(x, xb, (4096 * 768) / 4);
  k_transposeW<<<dim3(36, 12), 256, 0, stream>>>(Wqkv, WqkvT, 768, 2304);
  k_transposeW<<<dim3(12, 12), 256, 0, stream>>>(Wproj, WprojT, 768, 768);
  k_gemm<<<dim3(32, 18), 256, 0, stream>>>(xb, WqkvT, 4096, 2304, 768, 0, Qb,
                                           Kb, Vtb, nullptr, nullptr);
  k_attn<<<dim3(24, 96), 64, 0, stream>>>(Qb, Kb, Vtb, Ab, Op0, Op1, rs0, rs1);
  k_combine<<<1536, 256, 0, stream>>>(Op0, Op1, rs0, rs1, Ab);
  k_gemm<<<dim3(32, 6), 256, 0, stream>>>(Ab, WprojT, 4096, 768, 768, 1,
                                          nullptr, nullptr, nullptr, bproj, out);
}

// Round 3
// 143.144 us; speedup vs baseline: 1.4642x; 1.0007x over previous
//
#include <hip/hip_runtime.h>

typedef _Float16 f16;
typedef __attribute__((ext_vector_type(4))) _Float16 f16x4;
typedef __attribute__((ext_vector_type(8))) _Float16 f16x8;
typedef __attribute__((ext_vector_type(4))) float f32x4;

#define MFMA16(a, b, c) __builtin_amdgcn_mfma_f32_16x16x32_f16((a), (b), (c), 0, 0, 0)

__device__ __forceinline__ void gload_lds16(const void* g, void* l) {
  __builtin_amdgcn_global_load_lds(
      (const __attribute__((address_space(1))) void*)g,
      (__attribute__((address_space(3))) void*)l, 16, 0, 0);
}

// ---------------- convert fp32 -> f16 (vectorized) ----------------
__global__ __launch_bounds__(256) void k_convert(const float* __restrict__ in,
                                                 f16* __restrict__ out, int n4) {
  int i = blockIdx.x * blockDim.x + threadIdx.x;
  int stride = gridDim.x * blockDim.x;
  for (; i < n4; i += stride) {
    float4 v = ((const float4*)in)[i];
    f16x4 o;
    o.x = (f16)v.x; o.y = (f16)v.y; o.z = (f16)v.z; o.w = (f16)v.w;
    ((f16x4*)out)[i] = o;
  }
}

// ------------- transpose [K][N] fp32 -> [N][K] f16 (LDS tiled) -------------
__global__ __launch_bounds__(256) void k_transposeW(const float* __restrict__ in,
                                                    f16* __restrict__ out,
                                                    int K, int N) {
  __shared__ float tile[64][65];
  int n0 = blockIdx.x * 64, k0 = blockIdx.y * 64;
  int c = threadIdx.x & 63, r4 = threadIdx.x >> 6;
#pragma unroll
  for (int i = 0; i < 16; ++i) {
    int r = i * 4 + r4;
    tile[r][c] = in[(size_t)(k0 + r) * N + n0 + c];
  }
  __syncthreads();
#pragma unroll
  for (int i = 0; i < 16; ++i) {
    int r = i * 4 + r4;
    out[(size_t)(n0 + r) * K + k0 + c] = (f16)tile[c][r];
  }
}

// ---------------- 128x128 f16 MFMA GEMM, A[M][K] * BT[N][K]^T ----------------
// mode 0: scatter columns to Q/K [bh][t][d] (f16) and V transposed [bh][d][t]
// mode 1: out[row][col] = acc + bias[col] (fp32)
__global__ __launch_bounds__(256) void k_gemm(
    const f16* __restrict__ A, const f16* __restrict__ BT,
    int M, int N, int K, int mode,
    f16* __restrict__ Qo, f16* __restrict__ Ko, f16* __restrict__ Vt,
    const float* __restrict__ bias, float* __restrict__ out) {
  __shared__ f16 As[128 * 32];
  __shared__ f16 Bs[128 * 32];
  int tid = threadIdx.x;
  int wv = tid >> 6;
  int lane = tid & 63;
  int lr = lane & 15, lc = lane >> 4;
  int m0 = blockIdx.x * 128, n0 = blockIdx.y * 128;
  int wm = (wv >> 1) * 64, wn = (wv & 1) * 64;
  f32x4 acc[4][4] = {};
  int nK = K >> 5;
  for (int kt = 0; kt < nK; ++kt) {
    int k0 = kt << 5;
#pragma unroll
    for (int i = 0; i < 2; ++i) {
      int g = i * 256 + tid;
      gload_lds16(A + (size_t)(m0 + (g >> 2)) * K + k0 + (g & 3) * 8,
                  As + (size_t)(i * 256 + (tid & 192)) * 8);
    }
#pragma unroll
    for (int i = 0; i < 2; ++i) {
      int g = i * 256 + tid;
      gload_lds16(BT + (size_t)(n0 + (g >> 2)) * K + k0 + (g & 3) * 8,
                  Bs + (size_t)(i * 256 + (tid & 192)) * 8);
    }
    __syncthreads();
    f16x8 af[4], bf[4];
#pragma unroll
    for (int mi = 0; mi < 4; ++mi)
      af[mi] = *(const f16x8*)&As[(wm + mi * 16 + lr) * 32 + lc * 8];
#pragma unroll
    for (int ni = 0; ni < 4; ++ni)
      bf[ni] = *(const f16x8*)&Bs[(wn + ni * 16 + lr) * 32 + lc * 8];
#pragma unroll
    for (int mi = 0; mi < 4; ++mi)
#pragma unroll
      for (int ni = 0; ni < 4; ++ni)
        acc[mi][ni] = MFMA16(af[mi], bf[ni], acc[mi][ni]);
    __syncthreads();
  }
  if (mode == 0) {
#pragma unroll
    for (int ni = 0; ni < 4; ++ni) {
      int col = n0 + wn + ni * 16 + lr;
      int s = col / 768;
      int hh = (col - s * 768) >> 6;
      int d = col & 63;
      if (s == 2) {
        // V: write transposed [bh][d][t], 4 consecutive t per (mi)
#pragma unroll
        for (int mi = 0; mi < 4; ++mi) {
          int row0 = m0 + wm + mi * 16 + lc * 4;
          int b = row0 >> 11, t = row0 & 2047;
          f16x4 tv;
#pragma unroll
          for (int r = 0; r < 4; ++r) tv[r] = (f16)acc[mi][ni][r];
          *(f16x4*)&Vt[((size_t)(b * 12 + hh) * 64 + d) * 2048 + t] = tv;
        }
      } else {
        f16* dst = (s == 0) ? Qo : Ko;
#pragma unroll
        for (int mi = 0; mi < 4; ++mi)
#pragma unroll
          for (int r = 0; r < 4; ++r) {
            int row = m0 + wm + mi * 16 + lc * 4 + r;
            int b = row >> 11, t = row & 2047;
            dst[((size_t)(b * 12 + hh) * 2048 + t) * 64 + d] =
                (f16)acc[mi][ni][r];
          }
      }
    }
  } else {
#pragma unroll
    for (int ni = 0; ni < 4; ++ni) {
      int col = n0 + wn + ni * 16 + lr;
      float bv = bias[col];
#pragma unroll
      for (int mi = 0; mi < 4; ++mi)
#pragma unroll
        for (int r = 0; r < 4; ++r) {
          int row = m0 + wm + mi * 16 + lc * 4 + r;
          out[(size_t)row * 768 + col] = acc[mi][ni][r] + bv;
        }
    }
  }
}

// ---------------- causal softplus-normalized attention, split-K ----------------
// 1-wave blocks (64 thr), 32 q-rows per wave. grid (24 bh, 96):
//  y in [0,32):  qt = 32+y, keys [0,1024)   -> partial chunk0 (no mask)
//  y in [32,64): qt = 95-y, keys [1024,row] -> partial chunk1 (diag mask)
//  y in [64,96): qt = 95-y (rows < 1024), keys [0,row] -> final output
__global__ __launch_bounds__(64) void k_attn(
    const f16* __restrict__ Q, const f16* __restrict__ K,
    const f16* __restrict__ Vt, f16* __restrict__ Ab,
    float* __restrict__ Op0, float* __restrict__ Op1,
    float* __restrict__ rs0, float* __restrict__ rs1) {
  __shared__ f16 wb[2048];  // [32 rows][64 cols] XOR-swizzled P tile
  int lane = threadIdx.x;
  int lr = lane & 15, lc = lane >> 4;
  int bh = blockIdx.x;
  int y = blockIdx.y;
  int qt, kt0, nfull, mode;
  bool diag;
  if (y < 32)      { qt = 32 + y; kt0 = 0;  nfull = 16;                    diag = false; mode = 1; }
  else if (y < 64) { qt = 95 - y; kt0 = 16; nfull = (qt * 32 - 1024) >> 6; diag = true;  mode = 2; }
  else             { qt = 95 - y; kt0 = 0;  nfull = (qt * 32) >> 6;        diag = true;  mode = 0; }
  int qw = qt * 32;
  int b = bh / 12, h = bh - b * 12;
  const f16* Qp = Q + (size_t)bh * 2048 * 64;
  const f16* Kp = K + (size_t)bh * 2048 * 64;
  const f16* Vp = Vt + (size_t)bh * 64 * 2048;

  const f16 a16 = (f16)0.18033688f;  // 0.125 * log2(e): fold scale into Q
  f16x8 qf[2][2];
#pragma unroll
  for (int mi = 0; mi < 2; ++mi)
#pragma unroll
    for (int kh = 0; kh < 2; ++kh) {
      qf[mi][kh] =
          *(const f16x8*)&Qp[(size_t)(qw + mi * 16 + lr) * 64 + kh * 32 + lc * 8];
      qf[mi][kh] *= a16;
    }

  f32x4 o[2][4] = {};
  float rsl[2][4] = {};  // per-lane partial row sums

  auto do_tile = [&](int kb, bool maskit) {
    f32x4 s[2][4] = {};
#pragma unroll
    for (int ni = 0; ni < 4; ++ni)
#pragma unroll
      for (int kh = 0; kh < 2; ++kh) {
        f16x8 kf =
            *(const f16x8*)&Kp[(size_t)(kb + ni * 16 + lr) * 64 + kh * 32 + lc * 8];
        s[0][ni] = MFMA16(qf[0][kh], kf, s[0][ni]);
        s[1][ni] = MFMA16(qf[1][kh], kf, s[1][ni]);
      }
    // softplus(x) with z = x*log2e already: w = ln2*(max(z,0)+log2(1+2^-|z|))
#pragma unroll
    for (int mi = 0; mi < 2; ++mi)
#pragma unroll
      for (int ni = 0; ni < 4; ++ni) {
        int cb = ni * 16 + lr;
#pragma unroll
        for (int r = 0; r < 4; ++r) {
          int rloc = mi * 16 + lc * 4 + r;
          float z = s[mi][ni][r];
          float t = __builtin_amdgcn_exp2f(-fabsf(z));
          float w = (fmaxf(z, 0.f) + __builtin_amdgcn_logf(1.f + t)) *
                    0.6931471805599453f;
          if (maskit) w = (kb + cb <= qw + rloc) ? w : 0.f;
          rsl[mi][r] += w;
          wb[rloc * 64 + (((cb >> 3) ^ (rloc & 7)) << 3) + (cb & 7)] = (f16)w;
        }
      }
    // PV: A = P from LDS, B = Vt rows from global
#pragma unroll
    for (int kh = 0; kh < 2; ++kh) {
      f16x8 pa[2];
#pragma unroll
      for (int mi = 0; mi < 2; ++mi) {
        int rloc = mi * 16 + lr;
        pa[mi] =
            *(const f16x8*)&wb[rloc * 64 + ((((kh << 2) + lc) ^ (rloc & 7)) << 3)];
      }
#pragma unroll
      for (int di = 0; di < 4; ++di) {
        f16x8 vf =
            *(const f16x8*)&Vp[(size_t)(di * 16 + lr) * 2048 + kb + kh * 32 + lc * 8];
        o[0][di] = MFMA16(pa[0], vf, o[0][di]);
        o[1][di] = MFMA16(pa[1], vf, o[1][di]);
      }
    }
  };

  for (int kt = kt0; kt < kt0 + nfull; ++kt) do_tile(kt << 6, false);
  if (diag) do_tile(qw & ~63, true);

  // row-sum reduce across the 16 lr lanes (rows indexed by lc)
#pragma unroll
  for (int mi = 0; mi < 2; ++mi)
#pragma unroll
    for (int r = 0; r < 4; ++r) {
      float p = rsl[mi][r];
      p += __shfl_xor(p, 1);
      p += __shfl_xor(p, 2);
      p += __shfl_xor(p, 4);
      p += __shfl_xor(p, 8);
      rsl[mi][r] = p;
    }

  if (mode == 0) {
#pragma unroll
    for (int mi = 0; mi < 2; ++mi)
#pragma unroll
      for (int r = 0; r < 4; ++r) {
        int rloc = mi * 16 + lc * 4 + r;
        float inv = 1.0f / rsl[mi][r];
#pragma unroll
        for (int di = 0; di < 4; ++di)
          Ab[((size_t)b * 2048 + qw + rloc) * 768 + h * 64 + di * 16 + lr] =
              (f16)(o[mi][di][r] * inv);
      }
  } else {
    float* OP = (mode == 1) ? Op0 : Op1;
    float* RS = (mode == 1) ? rs0 : rs1;
    int pr0 = qw - 1024;
#pragma unroll
    for (int mi = 0; mi < 2; ++mi)
#pragma unroll
      for (int r = 0; r < 4; ++r) {
        int rloc = mi * 16 + lc * 4 + r;
        if (lr == 0) RS[bh * 1024 + pr0 + rloc] = rsl[mi][r];
#pragma unroll
        for (int di = 0; di < 4; ++di)
          OP[((size_t)bh * 1024 + pr0 + rloc) * 64 + di * 16 + lr] =
              o[mi][di][r];
      }
  }
}

// ---------------- combine split-K partials (rows 1024..2047) ----------------
__global__ __launch_bounds__(256) void k_combine(
    const float* __restrict__ Op0, const float* __restrict__ Op1,
    const float* __restrict__ rs0, const float* __restrict__ rs1,
    f16* __restrict__ Ab) {
  int i = blockIdx.x * 256 + threadIdx.x;  // one f32x4 per thread
  int e = i << 2;
  int bh = e >> 16;           // 1024*64 elems per bh
  int rem = e & 65535;
  int pr = rem >> 6, d = rem & 63;
  float inv = 1.0f / (rs0[(bh << 10) + pr] + rs1[(bh << 10) + pr]);
  float4 a = ((const float4*)Op0)[i];
  float4 c = ((const float4*)Op1)[i];
  f16x4 o4;
  o4[0] = (f16)((a.x + c.x) * inv);
  o4[1] = (f16)((a.y + c.y) * inv);
  o4[2] = (f16)((a.z + c.z) * inv);
  o4[3] = (f16)((a.w + c.w) * inv);
  int b = bh / 12, h = bh - b * 12;
  *(f16x4*)&Ab[((size_t)b * 2048 + 1024 + pr) * 768 + h * 64 + d] = o4;
}

// ---------------- host ----------------
extern "C" void kernel_launch(void* const* d_in, const int* in_sizes, int n_in,
                              void* d_out, int out_size, void* d_ws,
                              size_t ws_size, hipStream_t stream) {
  const float* x = (const float*)d_in[0];
  const float* Wqkv = (const float*)d_in[1];
  const float* Wproj = (const float*)d_in[2];
  const float* bproj = (const float*)d_in[3];
  float* out = (float*)d_out;
  char* ws = (char*)d_ws;

  f16* xb     = (f16*)(ws + 0);         // 4096x768 f16 = 6,291,456 B (dead after gemm1)
  float* Op0  = (float*)(ws + 0);       // alias: 24x1024x64 f32 = 6,291,456 B
  f16* WqkvT  = (f16*)(ws + 6291456);   // 2304x768
  f16* WprojT = (f16*)(ws + 9830400);   // 768x768
  f16* Qb     = (f16*)(ws + 11010048);  // 24x2048x64
  f16* Kb     = (f16*)(ws + 17301504);  // 24x2048x64
  f16* Vtb    = (f16*)(ws + 23592960);  // 24x64x2048 (written by gemm1)
  f16* Ab     = (f16*)(ws + 29884416);  // 4096x768
  float* Op1  = (float*)(ws + 36175872);// 24x1024x64 f32
  float* rs0  = (float*)(ws + 42467328);// 24x1024 f32
  float* rs1  = (float*)(ws + 42565632);// 24x1024 f32
  // total 42,663,936 B

  k_convert<<<1024, 256, 0, stream>>>(x, xb, (4096 * 768) / 4);
  k_transposeW<<<dim3(36, 12), 256, 0, stream>>>(Wqkv, WqkvT, 768, 2304);
  k_transposeW<<<dim3(12, 12), 256, 0, stream>>>(Wproj, WprojT, 768, 768);
  k_gemm<<<dim3(32, 18), 256, 0, stream>>>(xb, WqkvT, 4096, 2304, 768, 0, Qb,
                                           Kb, Vtb, nullptr, nullptr);
  k_attn<<<dim3(24, 96), 64, 0, stream>>>(Qb, Kb, Vtb, Ab, Op0, Op1, rs0, rs1);
  k_combine<<<1536, 256, 0, stream>>>(Op0, Op1, rs0, rs1, Ab);
  k_gemm<<<dim3(32, 6), 256, 0, stream>>>(Ab, WprojT, 4096, 768, 768, 1,
                                          nullptr, nullptr, nullptr, bproj, out);
}

// Round 4
// 127.391 us; speedup vs baseline: 1.6453x; 1.1237x over previous
//
#include <hip/hip_runtime.h>

typedef _Float16 f16;
typedef __attribute__((ext_vector_type(4))) _Float16 f16x4;
typedef __attribute__((ext_vector_type(8))) _Float16 f16x8;
typedef __attribute__((ext_vector_type(4))) float f32x4;

#define MFMA16(a, b, c) __builtin_amdgcn_mfma_f32_16x16x32_f16((a), (b), (c), 0, 0, 0)

__device__ __forceinline__ void gload_lds16(const void* g, void* l) {
  __builtin_amdgcn_global_load_lds(
      (const __attribute__((address_space(1))) void*)g,
      (__attribute__((address_space(3))) void*)l, 16, 0, 0);
}

// ------- fused prep: convert x -> f16, transpose Wqkv & Wproj -> [N][K] f16 -------
// blocks [0,768): convert (4 float4 per thread)
// blocks [768,1200): Wqkv transpose tiles; [1200,1344): Wproj transpose tiles
__global__ __launch_bounds__(256) void k_prep(
    const float* __restrict__ x, f16* __restrict__ xb,
    const float* __restrict__ Wq, f16* __restrict__ WqT,
    const float* __restrict__ Wp, f16* __restrict__ WpT) {
  __shared__ float tile[64][65];
  int bid = blockIdx.x;
  if (bid < 768) {
    int i = bid * 256 + threadIdx.x;
#pragma unroll
    for (int it = 0; it < 4; ++it, i += 768 * 256) {
      float4 v = ((const float4*)x)[i];
      f16x4 o;
      o[0] = (f16)v.x; o[1] = (f16)v.y; o[2] = (f16)v.z; o[3] = (f16)v.w;
      ((f16x4*)xb)[i] = o;
    }
    return;
  }
  const float* in; f16* out; int N, n0, k0;
  if (bid < 1200) {
    int t = bid - 768;
    in = Wq; out = WqT; N = 2304;
    n0 = (t % 36) * 64; k0 = (t / 36) * 64;
  } else {
    int t = bid - 1200;
    in = Wp; out = WpT; N = 768;
    n0 = (t % 12) * 64; k0 = (t / 12) * 64;
  }
  int c = threadIdx.x & 63, r4 = threadIdx.x >> 6;
#pragma unroll
  for (int i = 0; i < 16; ++i) {
    int r = i * 4 + r4;
    tile[r][c] = in[(size_t)(k0 + r) * N + n0 + c];
  }
  __syncthreads();
#pragma unroll
  for (int i = 0; i < 16; ++i) {
    int r = i * 4 + r4;
    out[(size_t)(n0 + r) * 768 + k0 + c] = (f16)tile[c][r];
  }
}

// ---------------- 128x128 f16 MFMA GEMM, A[M][K] * BT[N][K]^T ----------------
// mode 0: scatter columns to Q/K [bh][t][d] (f16) and V transposed [bh][d][t]
// mode 1: out[row][col] = acc + bias[col] (fp32)
__global__ __launch_bounds__(256) void k_gemm(
    const f16* __restrict__ A, const f16* __restrict__ BT,
    int M, int N, int K, int mode,
    f16* __restrict__ Qo, f16* __restrict__ Ko, f16* __restrict__ Vt,
    const float* __restrict__ bias, float* __restrict__ out) {
  __shared__ f16 As[128 * 32];
  __shared__ f16 Bs[128 * 32];
  int tid = threadIdx.x;
  int wv = tid >> 6;
  int lane = tid & 63;
  int lr = lane & 15, lc = lane >> 4;
  int m0 = blockIdx.x * 128, n0 = blockIdx.y * 128;
  int wm = (wv >> 1) * 64, wn = (wv & 1) * 64;
  f32x4 acc[4][4] = {};
  int nK = K >> 5;
  for (int kt = 0; kt < nK; ++kt) {
    int k0 = kt << 5;
#pragma unroll
    for (int i = 0; i < 2; ++i) {
      int g = i * 256 + tid;
      gload_lds16(A + (size_t)(m0 + (g >> 2)) * K + k0 + (g & 3) * 8,
                  As + (size_t)(i * 256 + (tid & 192)) * 8);
    }
#pragma unroll
    for (int i = 0; i < 2; ++i) {
      int g = i * 256 + tid;
      gload_lds16(BT + (size_t)(n0 + (g >> 2)) * K + k0 + (g & 3) * 8,
                  Bs + (size_t)(i * 256 + (tid & 192)) * 8);
    }
    __syncthreads();
    f16x8 af[4], bf[4];
#pragma unroll
    for (int mi = 0; mi < 4; ++mi)
      af[mi] = *(const f16x8*)&As[(wm + mi * 16 + lr) * 32 + lc * 8];
#pragma unroll
    for (int ni = 0; ni < 4; ++ni)
      bf[ni] = *(const f16x8*)&Bs[(wn + ni * 16 + lr) * 32 + lc * 8];
#pragma unroll
    for (int mi = 0; mi < 4; ++mi)
#pragma unroll
      for (int ni = 0; ni < 4; ++ni)
        acc[mi][ni] = MFMA16(af[mi], bf[ni], acc[mi][ni]);
    __syncthreads();
  }
  if (mode == 0) {
#pragma unroll
    for (int ni = 0; ni < 4; ++ni) {
      int col = n0 + wn + ni * 16 + lr;
      int s = col / 768;
      int hh = (col - s * 768) >> 6;
      int d = col & 63;
      if (s == 2) {
#pragma unroll
        for (int mi = 0; mi < 4; ++mi) {
          int row0 = m0 + wm + mi * 16 + lc * 4;
          int b = row0 >> 11, t = row0 & 2047;
          f16x4 tv;
#pragma unroll
          for (int r = 0; r < 4; ++r) tv[r] = (f16)acc[mi][ni][r];
          *(f16x4*)&Vt[((size_t)(b * 12 + hh) * 64 + d) * 2048 + t] = tv;
        }
      } else {
        f16* dst = (s == 0) ? Qo : Ko;
#pragma unroll
        for (int mi = 0; mi < 4; ++mi)
#pragma unroll
          for (int r = 0; r < 4; ++r) {
            int row = m0 + wm + mi * 16 + lc * 4 + r;
            int b = row >> 11, t = row & 2047;
            dst[((size_t)(b * 12 + hh) * 2048 + t) * 64 + d] =
                (f16)acc[mi][ni][r];
          }
      }
    }
  } else {
#pragma unroll
    for (int ni = 0; ni < 4; ++ni) {
      int col = n0 + wn + ni * 16 + lr;
      float bv = bias[col];
#pragma unroll
      for (int mi = 0; mi < 4; ++mi)
#pragma unroll
        for (int r = 0; r < 4; ++r) {
          int row = m0 + wm + mi * 16 + lc * 4 + r;
          out[(size_t)row * 768 + col] = acc[mi][ni][r] + bv;
        }
    }
  }
}

// ------------- causal softplus-normalized attention, in-block split-K -------------
// One 256-thread block per (bh, q-tile of 32 rows). 4 waves stride the k-tiles
// (kt = wv, wv+4, ...), accumulate private O/rowsum, combine in LDS at the end.
__global__ __launch_bounds__(256) void k_attn(const f16* __restrict__ Q,
                                              const f16* __restrict__ K,
                                              const f16* __restrict__ Vt,
                                              f16* __restrict__ Ab) {
  __shared__ f16 plds[4][2048];       // per-wave swizzled P tile
  __shared__ float comb[4][32][64];   // per-wave partial O
  __shared__ float rscomb[4][32];     // per-wave partial row sums
  int tid = threadIdx.x, wv = tid >> 6, lane = tid & 63;
  int lr = lane & 15, lc = lane >> 4;
  int bh = blockIdx.x;
  int qt = 63 - blockIdx.y;  // heavy blocks dispatch first
  int qw = qt * 32;
  int b = bh / 12, h = bh - b * 12;
  const f16* Qp = Q + (size_t)bh * 2048 * 64;
  const f16* Kp = K + (size_t)bh * 2048 * 64;
  const f16* Vp = Vt + (size_t)bh * 64 * 2048;

  const f16 a16 = (f16)0.18033688f;  // 0.125 * log2(e): fold scale into Q
  f16x8 qf[2][2];
#pragma unroll
  for (int mi = 0; mi < 2; ++mi)
#pragma unroll
    for (int kh = 0; kh < 2; ++kh) {
      qf[mi][kh] =
          *(const f16x8*)&Qp[(size_t)(qw + mi * 16 + lr) * 64 + kh * 32 + lc * 8];
      qf[mi][kh] *= a16;
    }

  f32x4 o[2][4] = {};
  float rsl[2][4] = {};
  f16* wb = plds[wv];
  int ntiles = (qw >> 6) + 1;

  for (int kt = wv; kt < ntiles; kt += 4) {
    int kb = kt << 6;
    bool maskit = (kt == ntiles - 1);
    // hoist V loads: independent of P, latency hides under QK^T + softplus
    f16x8 vf[2][4];
#pragma unroll
    for (int kh = 0; kh < 2; ++kh)
#pragma unroll
      for (int di = 0; di < 4; ++di)
        vf[kh][di] =
            *(const f16x8*)&Vp[(size_t)(di * 16 + lr) * 2048 + kb + kh * 32 + lc * 8];
    f32x4 s[2][4] = {};
#pragma unroll
    for (int ni = 0; ni < 4; ++ni)
#pragma unroll
      for (int kh = 0; kh < 2; ++kh) {
        f16x8 kf =
            *(const f16x8*)&Kp[(size_t)(kb + ni * 16 + lr) * 64 + kh * 32 + lc * 8];
        s[0][ni] = MFMA16(qf[0][kh], kf, s[0][ni]);
        s[1][ni] = MFMA16(qf[1][kh], kf, s[1][ni]);
      }
    // softplus with z = x*log2e: w = ln2*(max(z,0)+log2(1+2^-|z|))
#pragma unroll
    for (int mi = 0; mi < 2; ++mi)
#pragma unroll
      for (int ni = 0; ni < 4; ++ni) {
        int cb = ni * 16 + lr;
#pragma unroll
        for (int r = 0; r < 4; ++r) {
          int rloc = mi * 16 + lc * 4 + r;
          float z = s[mi][ni][r];
          float t = __builtin_amdgcn_exp2f(-fabsf(z));
          float w = (fmaxf(z, 0.f) + __builtin_amdgcn_logf(1.f + t)) *
                    0.6931471805599453f;
          if (maskit) w = (kb + cb <= qw + rloc) ? w : 0.f;
          rsl[mi][r] += w;
          wb[rloc * 64 + (((cb >> 3) ^ (rloc & 7)) << 3) + (cb & 7)] = (f16)w;
        }
      }
    // PV: A = P from LDS, B = hoisted V fragments
#pragma unroll
    for (int kh = 0; kh < 2; ++kh) {
      f16x8 pa[2];
#pragma unroll
      for (int mi = 0; mi < 2; ++mi) {
        int rloc = mi * 16 + lr;
        pa[mi] =
            *(const f16x8*)&wb[rloc * 64 + ((((kh << 2) + lc) ^ (rloc & 7)) << 3)];
      }
#pragma unroll
      for (int di = 0; di < 4; ++di) {
        o[0][di] = MFMA16(pa[0], vf[kh][di], o[0][di]);
        o[1][di] = MFMA16(pa[1], vf[kh][di], o[1][di]);
      }
    }
  }

  // intra-wave rowsum reduce across the 16 lr lanes
#pragma unroll
  for (int mi = 0; mi < 2; ++mi)
#pragma unroll
    for (int r = 0; r < 4; ++r) {
      float p = rsl[mi][r];
      p += __shfl_xor(p, 1);
      p += __shfl_xor(p, 2);
      p += __shfl_xor(p, 4);
      p += __shfl_xor(p, 8);
      rsl[mi][r] = p;
    }

  // deposit per-wave partials
#pragma unroll
  for (int mi = 0; mi < 2; ++mi)
#pragma unroll
    for (int r = 0; r < 4; ++r) {
      int row = mi * 16 + lc * 4 + r;
      if (lr == 0) rscomb[wv][row] = rsl[mi][r];
#pragma unroll
      for (int di = 0; di < 4; ++di)
        comb[wv][row][di * 16 + lr] = o[mi][di][r];
    }
  __syncthreads();

  // cross-wave combine: thread -> (row, 8 d's); normalize; store f16
  int row = tid >> 3, d0 = (tid & 7) << 3;
  float inv = 1.0f / (rscomb[0][row] + rscomb[1][row] + rscomb[2][row] +
                      rscomb[3][row]);
  f16x8 o8;
#pragma unroll
  for (int e = 0; e < 8; ++e) {
    float sum = comb[0][row][d0 + e] + comb[1][row][d0 + e] +
                comb[2][row][d0 + e] + comb[3][row][d0 + e];
    o8[e] = (f16)(sum * inv);
  }
  *(f16x8*)&Ab[((size_t)b * 2048 + qw + row) * 768 + h * 64 + d0] = o8;
}

// ---------------- host ----------------
extern "C" void kernel_launch(void* const* d_in, const int* in_sizes, int n_in,
                              void* d_out, int out_size, void* d_ws,
                              size_t ws_size, hipStream_t stream) {
  const float* x = (const float*)d_in[0];
  const float* Wqkv = (const float*)d_in[1];
  const float* Wproj = (const float*)d_in[2];
  const float* bproj = (const float*)d_in[3];
  float* out = (float*)d_out;
  char* ws = (char*)d_ws;

  f16* xb     = (f16*)(ws + 0);         // 4096x768
  f16* WqkvT  = (f16*)(ws + 6291456);   // 2304x768
  f16* WprojT = (f16*)(ws + 9830400);   // 768x768
  f16* Qb     = (f16*)(ws + 11010048);  // 24x2048x64
  f16* Kb     = (f16*)(ws + 17301504);  // 24x2048x64
  f16* Vtb    = (f16*)(ws + 23592960);  // 24x64x2048
  f16* Ab     = (f16*)(ws + 29884416);  // 4096x768
  // total 36,175,872 B

  k_prep<<<1344, 256, 0, stream>>>(x, xb, Wqkv, WqkvT, Wproj, WprojT);
  k_gemm<<<dim3(32, 18), 256, 0, stream>>>(xb, WqkvT, 4096, 2304, 768, 0, Qb,
                                           Kb, Vtb, nullptr, nullptr);
  k_attn<<<dim3(24, 64), 256, 0, stream>>>(Qb, Kb, Vtb, Ab);
  k_gemm<<<dim3(32, 6), 256, 0, stream>>>(Ab, WprojT, 4096, 768, 768, 1,
                                          nullptr, nullptr, nullptr, bproj, out);
}